// Round 10
// baseline (178.005 us; speedup 1.0000x reference)
//
#include <hip/hip_runtime.h>
#include <cstdint>
#include <cstddef>

typedef _Float16 half_t;
typedef __attribute__((ext_vector_type(8))) _Float16 f16x8;
typedef __attribute__((ext_vector_type(4))) _Float16 f16x4;
typedef __attribute__((ext_vector_type(4))) float f32x4;
typedef unsigned int uint_t;
typedef unsigned short ushort_t;

// Workspace offsets (bytes)
#define OFF_W1   0           // 184320 frag-lanes * 16B = 2,949,120
#define OFF_WD   2949120     // 368640 frag-lanes * 16B = 5,898,240
#define OFF_XHF  8847360     // 2,359,296 f16 = 4,718,592
#define OFF_XKH  13565952    // 4,718,592
#define OFF_VHF  18284544    // 160*256 f16 = 81,920
#define OFF_AG   18366464    // 3it*2bty*10u*1152c f32 = 276,480
#define WS_NEED  18642944

// ---------------- setup: W frags (f16 + f32) + xhf + xkh (one launch) ----------------
__global__ void k_setup(const float* __restrict__ x, const float* __restrict__ W,
                        half_t* __restrict__ w1, float* __restrict__ wd,
                        half_t* __restrict__ xhf, half_t* __restrict__ xkh) {
  int bid = blockIdx.x, tid = threadIdx.x;
  if (bid < 720) {                       // w1: B-frag f16 W (184320 frag-lanes)
    int gid = bid * 256 + tid;
    int ll = gid & 63, tile = gid >> 6;
    int nt = tile % 10, kt = tile / 10;
    int lmm = ll & 15, lgg = ll >> 4;
    f16x8 o;
#pragma unroll
    for (int j = 0; j < 8; ++j) {
      int k = kt * 32 + lgg * 8 + j;
      int i = k / 1152, c = k - i * 1152;
      o[j] = (half_t)W[((size_t)(c * 10 + nt) * 16 + lmm) * 8 + i];
    }
    *(f16x8*)(w1 + (size_t)gid * 8) = o;
  } else if (bid < 2160) {               // wd: D-layout f32 W (368640 frag-lanes)
    int g2 = (bid - 720) * 256 + tid;
    int ll = g2 & 63, tile = g2 >> 6;
    int nt = tile % 10, mt2 = tile / 10;
    int lmm = ll & 15, lgg = ll >> 4;
    float vv[4];
#pragma unroll
    for (int r = 0; r < 4; ++r) {
      int krow = mt2 * 16 + lgg * 4 + r;
      int i = krow / 1152, c = krow - i * 1152;
      vv[r] = W[((size_t)(c * 10 + nt) * 16 + lmm) * 8 + i];
    }
    *(float4*)(wd + (size_t)g2 * 4) = make_float4(vv[0], vv[1], vv[2], vv[3]);
  } else if (bid < 3312) {               // xhf: row-major f16 x (294912 x8-items)
    int t = (bid - 2160) * 256 + tid;
    const float4 a0 = *(const float4*)(x + (size_t)t * 8);
    const float4 a1 = *(const float4*)(x + (size_t)t * 8 + 4);
    f16x8 o;
    o[0] = (half_t)a0.x; o[1] = (half_t)a0.y; o[2] = (half_t)a0.z; o[3] = (half_t)a0.w;
    o[4] = (half_t)a1.x; o[5] = (half_t)a1.y; o[6] = (half_t)a1.z; o[7] = (half_t)a1.w;
    *(f16x8*)(xhf + (size_t)t * 8) = o;
  } else {                               // xkh: transpose tiles (2304 tiles)
    __shared__ float sh[32 * 33];
    int tb = bid - 3312;
    int k0 = (tb % 288) * 32, b0 = (tb / 288) * 32;
    int tx = tid & 31, ty = tid >> 5;
#pragma unroll
    for (int r = 0; r < 32; r += 8)
      sh[(ty + r) * 33 + tx] = x[(size_t)(b0 + ty + r) * 9216 + k0 + tx];
    __syncthreads();
#pragma unroll
    for (int r = 0; r < 32; r += 8)
      xkh[(size_t)(k0 + ty + r) * 256 + b0 + tx] = (half_t)sh[tx * 33 + ty + r];
  }
}

// ---------------- G1+squash: s = x*(cw.*W) over full K, squash, -> vhfT/out ----------------
// grid (16 mb, 10 nt), 256 thr = 4 waves; wave = 16 rows x 16 cols x K-chunk 2304.
__global__ __launch_bounds__(256) void k_g1sq(const half_t* __restrict__ xhf,
                                              const half_t* __restrict__ w1,
                                              const float* __restrict__ ag,
                                              half_t* __restrict__ vhfT,
                                              float* __restrict__ out, int it) {
  int mb = blockIdx.x, nt = blockIdx.y;
  int tid = threadIdx.x;
  int wv = tid >> 6, l = tid & 63, lm = l & 15, lgp = l >> 4;
  __shared__ __align__(16) half_t cwf[1152];   // cw[c][nt] — doubles as packed per-k scales
  __shared__ __align__(16) float red[4][64][4];

  // prologue: softmax over u of (sum of ag slices)/256, keep column nt
  for (int c = tid; c < 1152; c += 256) {
    float lv[10] = {0.f, 0.f, 0.f, 0.f, 0.f, 0.f, 0.f, 0.f, 0.f, 0.f};
    for (int t = 0; t < it; ++t)
#pragma unroll
      for (int bty = 0; bty < 2; ++bty) {
        const float* a = ag + ((size_t)(t * 2 + bty) * 10) * 1152 + c;
#pragma unroll
        for (int u = 0; u < 10; ++u) lv[u] += a[(size_t)u * 1152];
      }
    float mx = lv[0];
#pragma unroll
    for (int u = 1; u < 10; ++u) mx = fmaxf(mx, lv[u]);
    float ssum = 0.f, sel = 0.f;
#pragma unroll
    for (int u = 0; u < 10; ++u) {
      float e = __expf((lv[u] - mx) * (1.0f / 256.0f));
      ssum += e;
      if (u == nt) sel = e;   // static unroll -> cndmask, no dynamic reg index
    }
    cwf[c] = (half_t)(sel / ssum);
  }
  __syncthreads();

  f32x4 acc = {0.f, 0.f, 0.f, 0.f};
  const half_t* xrow = xhf + (size_t)(mb * 16 + lm) * 9216;
#pragma unroll 8
  for (int ktl = 0; ktl < 72; ++ktl) {
    int kt = wv * 72 + ktl;
    int ktc = (ktl >= 36) ? (ktl - 36) : ktl;   // kt % 36 (c-pattern repeats every 36 kt)
    f16x8 af = *(const f16x8*)(xrow + kt * 32 + lgp * 8);
    f16x8 wf = *(const f16x8*)(w1 + ((size_t)(kt * 10 + nt) * 64 + l) * 8);
    f16x8 cwk = *(const f16x8*)(&cwf[ktc * 32 + lgp * 8]);
    f16x8 bsc = wf * cwk;                        // 4x v_pk_mul_f16
    acc = __builtin_amdgcn_mfma_f32_16x16x32_f16(af, bsc, acc, 0, 0, 0);
  }
  *(f32x4*)&red[wv][l][0] = acc;
  __syncthreads();
  if (wv == 0) {
    float4 s;
    s.x = red[0][l][0] + red[1][l][0] + red[2][l][0] + red[3][l][0];
    s.y = red[0][l][1] + red[1][l][1] + red[2][l][1] + red[3][l][1];
    s.z = red[0][l][2] + red[1][l][2] + red[2][l][2] + red[3][l][2];
    s.w = red[0][l][3] + red[1][l][3] + red[2][l][3] + red[3][l][3];
    float4 n2 = make_float4(s.x * s.x, s.y * s.y, s.z * s.z, s.w * s.w);
#pragma unroll
    for (int off = 1; off < 16; off <<= 1) {   // sum over o (lm lanes)
      n2.x += __shfl_xor(n2.x, off);
      n2.y += __shfl_xor(n2.y, off);
      n2.z += __shfl_xor(n2.z, off);
      n2.w += __shfl_xor(n2.w, off);
    }
    float4 vv;
    vv.x = s.x * (n2.x / ((1.f + n2.x) * sqrtf(n2.x)));
    vv.y = s.y * (n2.y / ((1.f + n2.y) * sqrtf(n2.y)));
    vv.z = s.z * (n2.z / ((1.f + n2.z) * sqrtf(n2.z)));
    vv.w = s.w * (n2.w / ((1.f + n2.w) * sqrtf(n2.w)));
    if (it == 3) {   // rows b = mb*16 + lgp*4 + r, col = nt*16 + lm
      float* ob = out + (size_t)(mb * 16 + lgp * 4) * 160 + nt * 16 + lm;
      ob[0 * 160] = vv.x; ob[1 * 160] = vv.y; ob[2 * 160] = vv.z; ob[3 * 160] = vv.w;
    } else {         // vhfT[n][b], 4 consecutive b per lane -> 8B store
      f16x4 h;
      h[0] = (half_t)vv.x; h[1] = (half_t)vv.y; h[2] = (half_t)vv.z; h[3] = (half_t)vv.w;
      *(f16x4*)(vhfT + (size_t)(nt * 16 + lm) * 256 + mb * 16 + lgp * 4) = h;
    }
  }
}

// ---------------- G2: agreement, fully reduced per block -> ag[it][bty][u][c] ----------------
// grid (72 cb, 2 bty), 256 thr = 4 waves; block = 16 c's x all 8 i x 10 u, half of B.
__global__ __launch_bounds__(256) void k_g2(const half_t* __restrict__ xkh,
                                            const half_t* __restrict__ vhfT,
                                            const float* __restrict__ wd,
                                            float* __restrict__ ag, int it) {
  int cb = blockIdx.x, bty = blockIdx.y;
  int tid = threadIdx.x;
  int wv = tid >> 6, l = tid & 63, lm = l & 15, lgp = l >> 4;
  int mt0 = (wv * 2 + 0) * 72 + cb;   // k-row tiles for this wave's two i's
  int mt1 = (wv * 2 + 1) * 72 + cb;
  __shared__ float red2[4][16][10];

  f32x4 z = {0.f, 0.f, 0.f, 0.f};
  f32x4 acc[2][10];
#pragma unroll
  for (int ii = 0; ii < 2; ++ii)
#pragma unroll
    for (int nt = 0; nt < 10; ++nt) acc[ii][nt] = z;

#pragma unroll
  for (int bt = 0; bt < 4; ++bt) {
    int btg = bty * 4 + bt;
    f16x8 af0 = *(const f16x8*)(xkh + (size_t)(mt0 * 16 + lm) * 256 + btg * 32 + lgp * 8);
    f16x8 af1 = *(const f16x8*)(xkh + (size_t)(mt1 * 16 + lm) * 256 + btg * 32 + lgp * 8);
#pragma unroll
    for (int nt = 0; nt < 10; ++nt) {
      f16x8 bfr = *(const f16x8*)(vhfT + (size_t)(nt * 16 + lm) * 256 + btg * 32 + lgp * 8);
      acc[0][nt] = __builtin_amdgcn_mfma_f32_16x16x32_f16(af0, bfr, acc[0][nt], 0, 0, 0);
      acc[1][nt] = __builtin_amdgcn_mfma_f32_16x16x32_f16(af1, bfr, acc[1][nt], 0, 0, 0);
    }
  }
  // epilogue: dot with W (D-layout), reduce over o (lm) and this wave's two i's
  float4 pf[10];
#pragma unroll
  for (int nt = 0; nt < 10; ++nt) pf[nt] = make_float4(0.f, 0.f, 0.f, 0.f);
#pragma unroll
  for (int ii = 0; ii < 2; ++ii) {
    int mt = (ii == 0) ? mt0 : mt1;
#pragma unroll
    for (int nt = 0; nt < 10; ++nt) {
      float4 wdv = *(const float4*)(wd + ((size_t)(mt * 10 + nt) * 64 + l) * 4);
      float p0 = acc[ii][nt][0] * wdv.x;
      float p1 = acc[ii][nt][1] * wdv.y;
      float p2 = acc[ii][nt][2] * wdv.z;
      float p3 = acc[ii][nt][3] * wdv.w;
#pragma unroll
      for (int off = 1; off < 16; off <<= 1) {
        p0 += __shfl_xor(p0, off);
        p1 += __shfl_xor(p1, off);
        p2 += __shfl_xor(p2, off);
        p3 += __shfl_xor(p3, off);
      }
      pf[nt].x += p0; pf[nt].y += p1; pf[nt].z += p2; pf[nt].w += p3;
    }
  }
  if (lm == 0) {
#pragma unroll
    for (int nt = 0; nt < 10; ++nt) {
      red2[wv][lgp * 4 + 0][nt] = pf[nt].x;
      red2[wv][lgp * 4 + 1][nt] = pf[nt].y;
      red2[wv][lgp * 4 + 2][nt] = pf[nt].z;
      red2[wv][lgp * 4 + 3][nt] = pf[nt].w;
    }
  }
  __syncthreads();
  if (tid < 160) {   // final cross-wave sum, coalesced store: ag[it][bty][u][c]
    int u = tid >> 4, cc = tid & 15;
    float ss = red2[0][cc][u] + red2[1][cc][u] + red2[2][cc][u] + red2[3][cc][u];
    ag[((size_t)(it * 2 + bty) * 10 + u) * 1152 + cb * 16 + cc] = ss;
  }
}

extern "C" void kernel_launch(void* const* d_in, const int* in_sizes, int n_in,
                              void* d_out, int out_size, void* d_ws, size_t ws_size,
                              hipStream_t stream) {
  const float* x = (const float*)d_in[0];
  const float* W = (const float*)d_in[1];
  float* out = (float*)d_out;
  char* ws = (char*)d_ws;
  if (ws_size < WS_NEED) return;   // output stays poisoned -> visible failure

  half_t* w1  = (half_t*)(ws + OFF_W1);
  float*  wd  = (float*)(ws + OFF_WD);
  half_t* xhf = (half_t*)(ws + OFF_XHF);
  half_t* xkh = (half_t*)(ws + OFF_XKH);
  half_t* vhfT= (half_t*)(ws + OFF_VHF);
  float*  ag  = (float*)(ws + OFF_AG);

  k_setup<<<dim3(5616), dim3(256), 0, stream>>>(x, W, w1, wd, xhf, xkh);
  for (int it = 0; it < 4; ++it) {
    k_g1sq<<<dim3(16, 10), dim3(256), 0, stream>>>(xhf, w1, ag, vhfT, out, it);
    if (it < 3)
      k_g2<<<dim3(72, 2), dim3(256), 0, stream>>>(xkh, vhfT, wd, ag, it);
  }
}

// Round 11
// 148.965 us; speedup vs baseline: 1.1949x; 1.1949x over previous
//
#include <hip/hip_runtime.h>
#include <cstdint>
#include <cstddef>

typedef _Float16 half_t;
typedef __attribute__((ext_vector_type(8))) _Float16 f16x8;
typedef __attribute__((ext_vector_type(4))) _Float16 f16x4;
typedef __attribute__((ext_vector_type(4))) float f32x4;
typedef unsigned int uint_t;
typedef unsigned short ushort_t;

// Workspace offsets (bytes)
#define OFF_W1   0           // 184320 frag-lanes * 16B = 2,949,120
#define OFF_WD   2949120     // 368640 frag-lanes * 16B = 5,898,240
#define OFF_XHF  8847360     // 2,359,296 f16 = 4,718,592
#define OFF_XKH  13565952    // 4,718,592
#define OFF_VHF  18284544    // 160*256 f16 = 81,920
#define OFF_AG   18366464    // 3it*2bty*10u*1152c f32 = 276,480
#define WS_NEED  18642944

// ---------------- setup: W frags (f16 + f32) + xhf + xkh (one launch) ----------------
__global__ void k_setup(const float* __restrict__ x, const float* __restrict__ W,
                        half_t* __restrict__ w1, float* __restrict__ wd,
                        half_t* __restrict__ xhf, half_t* __restrict__ xkh) {
  int bid = blockIdx.x, tid = threadIdx.x;
  if (bid < 720) {                       // w1: B-frag f16 W (184320 frag-lanes)
    int gid = bid * 256 + tid;
    int ll = gid & 63, tile = gid >> 6;
    int nt = tile % 10, kt = tile / 10;
    int lmm = ll & 15, lgg = ll >> 4;
    f16x8 o;
#pragma unroll
    for (int j = 0; j < 8; ++j) {
      int k = kt * 32 + lgg * 8 + j;
      int i = k / 1152, c = k - i * 1152;
      o[j] = (half_t)W[((size_t)(c * 10 + nt) * 16 + lmm) * 8 + i];
    }
    *(f16x8*)(w1 + (size_t)gid * 8) = o;
  } else if (bid < 2160) {               // wd: D-layout f32 W (368640 frag-lanes)
    int g2 = (bid - 720) * 256 + tid;
    int ll = g2 & 63, tile = g2 >> 6;
    int nt = tile % 10, mt2 = tile / 10;
    int lmm = ll & 15, lgg = ll >> 4;
    float vv[4];
#pragma unroll
    for (int r = 0; r < 4; ++r) {
      int krow = mt2 * 16 + lgg * 4 + r;
      int i = krow / 1152, c = krow - i * 1152;
      vv[r] = W[((size_t)(c * 10 + nt) * 16 + lmm) * 8 + i];
    }
    *(float4*)(wd + (size_t)g2 * 4) = make_float4(vv[0], vv[1], vv[2], vv[3]);
  } else if (bid < 3312) {               // xhf: row-major f16 x (294912 x8-items)
    int t = (bid - 2160) * 256 + tid;
    const float4 a0 = *(const float4*)(x + (size_t)t * 8);
    const float4 a1 = *(const float4*)(x + (size_t)t * 8 + 4);
    f16x8 o;
    o[0] = (half_t)a0.x; o[1] = (half_t)a0.y; o[2] = (half_t)a0.z; o[3] = (half_t)a0.w;
    o[4] = (half_t)a1.x; o[5] = (half_t)a1.y; o[6] = (half_t)a1.z; o[7] = (half_t)a1.w;
    *(f16x8*)(xhf + (size_t)t * 8) = o;
  } else {                               // xkh: transpose tiles (2304 tiles)
    __shared__ float sh[32 * 33];
    int tb = bid - 3312;
    int k0 = (tb % 288) * 32, b0 = (tb / 288) * 32;
    int tx = tid & 31, ty = tid >> 5;
#pragma unroll
    for (int r = 0; r < 32; r += 8)
      sh[(ty + r) * 33 + tx] = x[(size_t)(b0 + ty + r) * 9216 + k0 + tx];
    __syncthreads();
#pragma unroll
    for (int r = 0; r < 32; r += 8)
      xkh[(size_t)(k0 + ty + r) * 256 + b0 + tx] = (half_t)sh[tx * 33 + ty + r];
  }
}

// ---------------- G1+squash: 16 waves, wave K-chunk 576 (18 kt) ----------------
// grid (16 mb, 10 nt), 1024 thr.
__global__ __launch_bounds__(1024) void k_g1sq(const half_t* __restrict__ xhf,
                                               const half_t* __restrict__ w1,
                                               const float* __restrict__ ag,
                                               half_t* __restrict__ vhfT,
                                               float* __restrict__ out, int it) {
  int mb = blockIdx.x, nt = blockIdx.y;
  int tid = threadIdx.x;
  int wv = tid >> 6, l = tid & 63, lm = l & 15, lgp = l >> 4;
  __shared__ __align__(16) half_t cwf[1152];   // cw[c][nt] — packed per-k scale vector
  __shared__ __align__(16) float red[16][64][4];

  // prologue: softmax over u of (sum of ag slices)/256, keep column nt
  for (int c = tid; c < 1152; c += 1024) {
    float lv[10] = {0.f, 0.f, 0.f, 0.f, 0.f, 0.f, 0.f, 0.f, 0.f, 0.f};
    for (int t = 0; t < it; ++t)
#pragma unroll
      for (int bty = 0; bty < 2; ++bty) {
        const float* a = ag + ((size_t)(t * 2 + bty) * 10) * 1152 + c;
#pragma unroll
        for (int u = 0; u < 10; ++u) lv[u] += a[(size_t)u * 1152];
      }
    float mx = lv[0];
#pragma unroll
    for (int u = 1; u < 10; ++u) mx = fmaxf(mx, lv[u]);
    float ssum = 0.f, sel = 0.f;
#pragma unroll
    for (int u = 0; u < 10; ++u) {
      float e = __expf((lv[u] - mx) * (1.0f / 256.0f));
      ssum += e;
      if (u == nt) sel = e;
    }
    cwf[c] = (half_t)(sel / ssum);
  }
  __syncthreads();

  f32x4 acc0 = {0.f, 0.f, 0.f, 0.f};
  f32x4 acc1 = {0.f, 0.f, 0.f, 0.f};
  const half_t* xrow = xhf + (size_t)(mb * 16 + lm) * 9216;
  int ktc0 = (wv & 1) * 18;   // kt % 36 base (k-c pattern repeats every 36 kt)
#pragma unroll
  for (int ktl = 0; ktl < 18; ktl += 2) {   // two independent acc chains
    int kt = wv * 18 + ktl;
    f16x8 afA = *(const f16x8*)(xrow + (size_t)kt * 32 + lgp * 8);
    f16x8 wfA = *(const f16x8*)(w1 + ((size_t)(kt * 10 + nt) * 64 + l) * 8);
    f16x8 afB = *(const f16x8*)(xrow + (size_t)(kt + 1) * 32 + lgp * 8);
    f16x8 wfB = *(const f16x8*)(w1 + ((size_t)((kt + 1) * 10 + nt) * 64 + l) * 8);
    f16x8 cwA = *(const f16x8*)(&cwf[(ktc0 + ktl) * 32 + lgp * 8]);
    f16x8 cwB = *(const f16x8*)(&cwf[(ktc0 + ktl + 1) * 32 + lgp * 8]);
    acc0 = __builtin_amdgcn_mfma_f32_16x16x32_f16(afA, wfA * cwA, acc0, 0, 0, 0);
    acc1 = __builtin_amdgcn_mfma_f32_16x16x32_f16(afB, wfB * cwB, acc1, 0, 0, 0);
  }
  acc0[0] += acc1[0]; acc0[1] += acc1[1]; acc0[2] += acc1[2]; acc0[3] += acc1[3];
  *(f32x4*)&red[wv][l][0] = acc0;
  __syncthreads();
  if (wv == 0) {
    float4 s = make_float4(0.f, 0.f, 0.f, 0.f);
#pragma unroll
    for (int w = 0; w < 16; ++w) {
      s.x += red[w][l][0]; s.y += red[w][l][1];
      s.z += red[w][l][2]; s.w += red[w][l][3];
    }
    float4 n2 = make_float4(s.x * s.x, s.y * s.y, s.z * s.z, s.w * s.w);
#pragma unroll
    for (int off = 1; off < 16; off <<= 1) {   // sum over o (lm lanes)
      n2.x += __shfl_xor(n2.x, off);
      n2.y += __shfl_xor(n2.y, off);
      n2.z += __shfl_xor(n2.z, off);
      n2.w += __shfl_xor(n2.w, off);
    }
    float4 vv;
    vv.x = s.x * (n2.x / ((1.f + n2.x) * sqrtf(n2.x)));
    vv.y = s.y * (n2.y / ((1.f + n2.y) * sqrtf(n2.y)));
    vv.z = s.z * (n2.z / ((1.f + n2.z) * sqrtf(n2.z)));
    vv.w = s.w * (n2.w / ((1.f + n2.w) * sqrtf(n2.w)));
    if (it == 3) {   // rows b = mb*16 + lgp*4 + r, col = nt*16 + lm
      float* ob = out + (size_t)(mb * 16 + lgp * 4) * 160 + nt * 16 + lm;
      ob[0 * 160] = vv.x; ob[1 * 160] = vv.y; ob[2 * 160] = vv.z; ob[3 * 160] = vv.w;
    } else {         // vhfT[n][b]
      f16x4 h;
      h[0] = (half_t)vv.x; h[1] = (half_t)vv.y; h[2] = (half_t)vv.z; h[3] = (half_t)vv.w;
      *(f16x4*)(vhfT + (size_t)(nt * 16 + lm) * 256 + mb * 16 + lgp * 4) = h;
    }
  }
}

// ---------------- G2: 8 waves, one i per wave -> ag[it][bty][u][c] ----------------
// grid (72 cb, 2 bty), 512 thr.
__global__ __launch_bounds__(512) void k_g2(const half_t* __restrict__ xkh,
                                            const half_t* __restrict__ vhfT,
                                            const float* __restrict__ wd,
                                            float* __restrict__ ag, int it) {
  int cb = blockIdx.x, bty = blockIdx.y;
  int tid = threadIdx.x;
  int wv = tid >> 6, l = tid & 63, lm = l & 15, lgp = l >> 4;
  int mt = wv * 72 + cb;               // this wave's i = wv, k-row tile
  __shared__ float red2[8][16][10];

  f32x4 z = {0.f, 0.f, 0.f, 0.f};
  f32x4 acc[10];
#pragma unroll
  for (int nt = 0; nt < 10; ++nt) acc[nt] = z;

#pragma unroll
  for (int bt = 0; bt < 4; ++bt) {
    int btg = bty * 4 + bt;
    f16x8 af = *(const f16x8*)(xkh + (size_t)(mt * 16 + lm) * 256 + btg * 32 + lgp * 8);
#pragma unroll
    for (int nt = 0; nt < 10; ++nt) {
      f16x8 bfr = *(const f16x8*)(vhfT + (size_t)(nt * 16 + lm) * 256 + btg * 32 + lgp * 8);
      acc[nt] = __builtin_amdgcn_mfma_f32_16x16x32_f16(af, bfr, acc[nt], 0, 0, 0);
    }
  }
  // epilogue: dot with W (D-layout), reduce over o (lm lanes)
#pragma unroll
  for (int nt = 0; nt < 10; ++nt) {
    float4 wdv = *(const float4*)(wd + ((size_t)(mt * 10 + nt) * 64 + l) * 4);
    float p0 = acc[nt][0] * wdv.x;
    float p1 = acc[nt][1] * wdv.y;
    float p2 = acc[nt][2] * wdv.z;
    float p3 = acc[nt][3] * wdv.w;
#pragma unroll
    for (int off = 1; off < 16; off <<= 1) {
      p0 += __shfl_xor(p0, off);
      p1 += __shfl_xor(p1, off);
      p2 += __shfl_xor(p2, off);
      p3 += __shfl_xor(p3, off);
    }
    if (lm == 0) {
      red2[wv][lgp * 4 + 0][nt] = p0;
      red2[wv][lgp * 4 + 1][nt] = p1;
      red2[wv][lgp * 4 + 2][nt] = p2;
      red2[wv][lgp * 4 + 3][nt] = p3;
    }
  }
  __syncthreads();
  if (tid < 160) {   // final cross-wave (over i) sum, coalesced store: ag[it][bty][u][c]
    int u = tid >> 4, cc = tid & 15;
    float ss = 0.f;
#pragma unroll
    for (int w = 0; w < 8; ++w) ss += red2[w][cc][u];
    ag[((size_t)(it * 2 + bty) * 10 + u) * 1152 + cb * 16 + cc] = ss;
  }
}

extern "C" void kernel_launch(void* const* d_in, const int* in_sizes, int n_in,
                              void* d_out, int out_size, void* d_ws, size_t ws_size,
                              hipStream_t stream) {
  const float* x = (const float*)d_in[0];
  const float* W = (const float*)d_in[1];
  float* out = (float*)d_out;
  char* ws = (char*)d_ws;
  if (ws_size < WS_NEED) return;   // output stays poisoned -> visible failure

  half_t* w1  = (half_t*)(ws + OFF_W1);
  float*  wd  = (float*)(ws + OFF_WD);
  half_t* xhf = (half_t*)(ws + OFF_XHF);
  half_t* xkh = (half_t*)(ws + OFF_XKH);
  half_t* vhfT= (half_t*)(ws + OFF_VHF);
  float*  ag  = (float*)(ws + OFF_AG);

  k_setup<<<dim3(5616), dim3(256), 0, stream>>>(x, W, w1, wd, xhf, xkh);
  for (int it = 0; it < 4; ++it) {
    k_g1sq<<<dim3(16, 10), dim3(1024), 0, stream>>>(xhf, w1, ag, vhfT, out, it);
    if (it < 3)
      k_g2<<<dim3(72, 2), dim3(512), 0, stream>>>(xkh, vhfT, wd, ag, it);
  }
}

// Round 13
// 141.078 us; speedup vs baseline: 1.2617x; 1.0559x over previous
//
#include <hip/hip_runtime.h>
#include <cstdint>
#include <cstddef>

typedef _Float16 half_t;
typedef __attribute__((ext_vector_type(8))) _Float16 f16x8;
typedef __attribute__((ext_vector_type(4))) _Float16 f16x4;
typedef __attribute__((ext_vector_type(4))) float f32x4;
typedef unsigned int uint_t;
typedef unsigned short ushort_t;

// Workspace offsets (bytes)
#define OFF_W1   0           // 184320 frag-lanes * 16B = 2,949,120
#define OFF_WD   2949120     // 368640 frag-lanes * 16B = 5,898,240
#define OFF_XHF  8847360     // 2,359,296 f16 = 4,718,592
#define OFF_XKH  13565952    // 4,718,592
#define OFF_VHF  18284544    // 160*256 f16 = 81,920
#define OFF_AG   18366464    // 3it*2bty*10u*1152c f32 = 276,480
#define WS_NEED  18642944

// async 16B/lane global->LDS (lds dest = wave-uniform base + lane*16, HW-enforced)
__device__ __forceinline__ void gload16(const void* g, void* l) {
  __builtin_amdgcn_global_load_lds(
      (const __attribute__((address_space(1))) unsigned int*)g,
      (__attribute__((address_space(3))) unsigned int*)l, 16, 0, 0);
}

// ---------------- setup: W frags (f16 + f32) + xhf + xkh (one launch) ----------------
__global__ void k_setup(const float* __restrict__ x, const float* __restrict__ W,
                        half_t* __restrict__ w1, float* __restrict__ wd,
                        half_t* __restrict__ xhf, half_t* __restrict__ xkh) {
  int bid = blockIdx.x, tid = threadIdx.x;
  if (bid < 720) {                       // w1: B-frag f16 W (184320 frag-lanes)
    int gid = bid * 256 + tid;
    int ll = gid & 63, tile = gid >> 6;
    int nt = tile % 10, kt = tile / 10;
    int lmm = ll & 15, lgg = ll >> 4;
    f16x8 o;
#pragma unroll
    for (int j = 0; j < 8; ++j) {
      int k = kt * 32 + lgg * 8 + j;
      int i = k / 1152, c = k - i * 1152;
      o[j] = (half_t)W[((size_t)(c * 10 + nt) * 16 + lmm) * 8 + i];
    }
    *(f16x8*)(w1 + (size_t)gid * 8) = o;
  } else if (bid < 2160) {               // wd: D-layout f32 W (368640 frag-lanes)
    int g2 = (bid - 720) * 256 + tid;
    int ll = g2 & 63, tile = g2 >> 6;
    int nt = tile % 10, mt2 = tile / 10;
    int lmm = ll & 15, lgg = ll >> 4;
    float vv[4];
#pragma unroll
    for (int r = 0; r < 4; ++r) {
      int krow = mt2 * 16 + lgg * 4 + r;
      int i = krow / 1152, c = krow - i * 1152;
      vv[r] = W[((size_t)(c * 10 + nt) * 16 + lmm) * 8 + i];
    }
    *(float4*)(wd + (size_t)g2 * 4) = make_float4(vv[0], vv[1], vv[2], vv[3]);
  } else if (bid < 3312) {               // xhf: row-major f16 x (294912 x8-items)
    int t = (bid - 2160) * 256 + tid;
    const float4 a0 = *(const float4*)(x + (size_t)t * 8);
    const float4 a1 = *(const float4*)(x + (size_t)t * 8 + 4);
    f16x8 o;
    o[0] = (half_t)a0.x; o[1] = (half_t)a0.y; o[2] = (half_t)a0.z; o[3] = (half_t)a0.w;
    o[4] = (half_t)a1.x; o[5] = (half_t)a1.y; o[6] = (half_t)a1.z; o[7] = (half_t)a1.w;
    *(f16x8*)(xhf + (size_t)t * 8) = o;
  } else {                               // xkh: transpose tiles (2304 tiles)
    __shared__ float sh[32 * 33];
    int tb = bid - 3312;
    int k0 = (tb % 288) * 32, b0 = (tb / 288) * 32;
    int tx = tid & 31, ty = tid >> 5;
#pragma unroll
    for (int r = 0; r < 32; r += 8)
      sh[(ty + r) * 33 + tx] = x[(size_t)(b0 + ty + r) * 9216 + k0 + tx];
    __syncthreads();
#pragma unroll
    for (int r = 0; r < 32; r += 8)
      xkh[(size_t)(k0 + ty + r) * 256 + b0 + tx] = (half_t)sh[tx * 33 + ty + r];
  }
}

// ---------------- G1+squash: 16 waves, race-free 3-buffer async staging ----------------
// grid (16 mb, 10 nt), 1024 thr; wave = 16 rows x 16 cols x 18 kt.
__global__ __launch_bounds__(1024) void k_g1sq(const half_t* __restrict__ xhf,
                                               const half_t* __restrict__ w1,
                                               const float* __restrict__ ag,
                                               half_t* __restrict__ vhfT,
                                               float* __restrict__ out, int it) {
  int mb = blockIdx.x, nt = blockIdx.y;
  int tid = threadIdx.x;
  int wv = tid >> 6, l = tid & 63, lm = l & 15, lgp = l >> 4;
  __shared__ __align__(16) half_t cwf[1152];            // cw[c][nt] per-k scale vector
  __shared__ __align__(16) half_t stage[16][3][2][512]; // [wave][buf][x/w][1KB] = 96KB
  __shared__ __align__(16) float red[16][64][4];

  // prologue: softmax over u of (sum of ag slices)/256, keep column nt
  for (int c = tid; c < 1152; c += 1024) {
    float lv[10] = {0.f, 0.f, 0.f, 0.f, 0.f, 0.f, 0.f, 0.f, 0.f, 0.f};
    for (int t = 0; t < it; ++t)
#pragma unroll
      for (int bty = 0; bty < 2; ++bty) {
        const float* a = ag + ((size_t)(t * 2 + bty) * 10) * 1152 + c;
#pragma unroll
        for (int u = 0; u < 10; ++u) lv[u] += a[(size_t)u * 1152];
      }
    float mx = lv[0];
#pragma unroll
    for (int u = 1; u < 10; ++u) mx = fmaxf(mx, lv[u]);
    float ssum = 0.f, sel = 0.f;
#pragma unroll
    for (int u = 0; u < 10; ++u) {
      float e = __expf((lv[u] - mx) * (1.0f / 256.0f));
      ssum += e;
      if (u == nt) sel = e;
    }
    cwf[c] = (half_t)(sel / ssum);
  }
  __syncthreads();   // drains vmcnt fully -> counted waits below see only our loads

  // per-wave stage: x-tile lane l -> row l>>2, colgrp l&3; w-tile frag-linear lane l
  const half_t* xbase = xhf + (size_t)(mb * 16 + (l >> 2)) * 9216 + (l & 3) * 8;
  int kt0 = wv * 18;
  int ktc0 = (wv & 1) * 18;   // kt % 36 base (k->c pattern repeats every 36 kt)
#define ISSUE(J)                                                                     \
  do {                                                                               \
    int kt_ = kt0 + (J);                                                             \
    gload16(xbase + (size_t)kt_ * 32, &stage[wv][(J) % 3][0][0]);                    \
    gload16(w1 + ((size_t)(kt_ * 10 + nt) * 512) + l * 8, &stage[wv][(J) % 3][1][0]);\
  } while (0)

  ISSUE(0);
  ISSUE(1);
  ISSUE(2);   // 6 outstanding, 3 buffers

  f32x4 acc0 = {0.f, 0.f, 0.f, 0.f};
  f32x4 acc1 = {0.f, 0.f, 0.f, 0.f};
#pragma unroll
  for (int j = 0; j < 18; ++j) {
    const int buf = j % 3;
    // wait for tile j (oldest). outstanding tiles beyond j: min(j+2,17)-j.
    if (j <= 15) {
      asm volatile("s_waitcnt vmcnt(4)" ::: "memory");
    } else if (j == 16) {
      asm volatile("s_waitcnt vmcnt(2)" ::: "memory");
    } else {
      asm volatile("s_waitcnt vmcnt(0)" ::: "memory");
    }
    __builtin_amdgcn_sched_barrier(0);
    f16x8 af = *(const f16x8*)&stage[wv][buf][0][lm * 32 + lgp * 8];
    f16x8 wf = *(const f16x8*)&stage[wv][buf][1][l * 8];
    f16x8 cwk = *(const f16x8*)(&cwf[(ktc0 + j) * 32 + lgp * 8]);
    if ((j & 1) == 0) acc0 = __builtin_amdgcn_mfma_f32_16x16x32_f16(af, wf * cwk, acc0, 0, 0, 0);
    else              acc1 = __builtin_amdgcn_mfma_f32_16x16x32_f16(af, wf * cwk, acc1, 0, 0, 0);
    __builtin_amdgcn_sched_barrier(0);
    // issue-after-consume: MFMA's lgkmcnt wait retired the ds_reads of buf j%3,
    // so refilling the SAME buffer now is race-free.
    if (j + 3 < 18) ISSUE(j + 3);
    __builtin_amdgcn_sched_barrier(0);
  }
#undef ISSUE
  acc0[0] += acc1[0]; acc0[1] += acc1[1]; acc0[2] += acc1[2]; acc0[3] += acc1[3];
  *(f32x4*)&red[wv][l][0] = acc0;
  __syncthreads();
  if (wv == 0) {
    float4 s = make_float4(0.f, 0.f, 0.f, 0.f);
#pragma unroll
    for (int w = 0; w < 16; ++w) {
      s.x += red[w][l][0]; s.y += red[w][l][1];
      s.z += red[w][l][2]; s.w += red[w][l][3];
    }
    float4 n2 = make_float4(s.x * s.x, s.y * s.y, s.z * s.z, s.w * s.w);
#pragma unroll
    for (int off = 1; off < 16; off <<= 1) {   // sum over o (lm lanes)
      n2.x += __shfl_xor(n2.x, off);
      n2.y += __shfl_xor(n2.y, off);
      n2.z += __shfl_xor(n2.z, off);
      n2.w += __shfl_xor(n2.w, off);
    }
    float4 vv;
    vv.x = s.x * (n2.x / ((1.f + n2.x) * sqrtf(n2.x)));
    vv.y = s.y * (n2.y / ((1.f + n2.y) * sqrtf(n2.y)));
    vv.z = s.z * (n2.z / ((1.f + n2.z) * sqrtf(n2.z)));
    vv.w = s.w * (n2.w / ((1.f + n2.w) * sqrtf(n2.w)));
    if (it == 3) {   // rows b = mb*16 + lgp*4 + r, col = nt*16 + lm
      float* ob = out + (size_t)(mb * 16 + lgp * 4) * 160 + nt * 16 + lm;
      ob[0 * 160] = vv.x; ob[1 * 160] = vv.y; ob[2 * 160] = vv.z; ob[3 * 160] = vv.w;
    } else {         // vhfT[n][b]
      f16x4 h;
      h[0] = (half_t)vv.x; h[1] = (half_t)vv.y; h[2] = (half_t)vv.z; h[3] = (half_t)vv.w;
      *(f16x4*)(vhfT + (size_t)(nt * 16 + lm) * 256 + mb * 16 + lgp * 4) = h;
    }
  }
}

// ---------------- G2: 8 waves, one i per wave -> ag[it][bty][u][c] ----------------
// grid (72 cb, 2 bty), 512 thr.
__global__ __launch_bounds__(512) void k_g2(const half_t* __restrict__ xkh,
                                            const half_t* __restrict__ vhfT,
                                            const float* __restrict__ wd,
                                            float* __restrict__ ag, int it) {
  int cb = blockIdx.x, bty = blockIdx.y;
  int tid = threadIdx.x;
  int wv = tid >> 6, l = tid & 63, lm = l & 15, lgp = l >> 4;
  int mt = wv * 72 + cb;               // this wave's i = wv, k-row tile
  __shared__ float red2[8][16][10];

  f32x4 z = {0.f, 0.f, 0.f, 0.f};
  f32x4 acc[10];
#pragma unroll
  for (int nt = 0; nt < 10; ++nt) acc[nt] = z;

#pragma unroll
  for (int bt = 0; bt < 4; ++bt) {
    int btg = bty * 4 + bt;
    f16x8 af = *(const f16x8*)(xkh + (size_t)(mt * 16 + lm) * 256 + btg * 32 + lgp * 8);
#pragma unroll
    for (int nt = 0; nt < 10; ++nt) {
      f16x8 bfr = *(const f16x8*)(vhfT + (size_t)(nt * 16 + lm) * 256 + btg * 32 + lgp * 8);
      acc[nt] = __builtin_amdgcn_mfma_f32_16x16x32_f16(af, bfr, acc[nt], 0, 0, 0);
    }
  }
  // epilogue: dot with W (D-layout), reduce over o (lm lanes)
#pragma unroll
  for (int nt = 0; nt < 10; ++nt) {
    float4 wdv = *(const float4*)(wd + ((size_t)(mt * 10 + nt) * 64 + l) * 4);
    float p0 = acc[nt][0] * wdv.x;
    float p1 = acc[nt][1] * wdv.y;
    float p2 = acc[nt][2] * wdv.z;
    float p3 = acc[nt][3] * wdv.w;
#pragma unroll
    for (int off = 1; off < 16; off <<= 1) {
      p0 += __shfl_xor(p0, off);
      p1 += __shfl_xor(p1, off);
      p2 += __shfl_xor(p2, off);
      p3 += __shfl_xor(p3, off);
    }
    if (lm == 0) {
      red2[wv][lgp * 4 + 0][nt] = p0;
      red2[wv][lgp * 4 + 1][nt] = p1;
      red2[wv][lgp * 4 + 2][nt] = p2;
      red2[wv][lgp * 4 + 3][nt] = p3;
    }
  }
  __syncthreads();
  if (tid < 160) {   // final cross-wave (over i) sum, coalesced store: ag[it][bty][u][c]
    int u = tid >> 4, cc = tid & 15;
    float ss = 0.f;
#pragma unroll
    for (int w = 0; w < 8; ++w) ss += red2[w][cc][u];
    ag[((size_t)(it * 2 + bty) * 10 + u) * 1152 + cb * 16 + cc] = ss;
  }
}

extern "C" void kernel_launch(void* const* d_in, const int* in_sizes, int n_in,
                              void* d_out, int out_size, void* d_ws, size_t ws_size,
                              hipStream_t stream) {
  const float* x = (const float*)d_in[0];
  const float* W = (const float*)d_in[1];
  float* out = (float*)d_out;
  char* ws = (char*)d_ws;
  if (ws_size < WS_NEED) return;   // output stays poisoned -> visible failure

  half_t* w1  = (half_t*)(ws + OFF_W1);
  float*  wd  = (float*)(ws + OFF_WD);
  half_t* xhf = (half_t*)(ws + OFF_XHF);
  half_t* xkh = (half_t*)(ws + OFF_XKH);
  half_t* vhfT= (half_t*)(ws + OFF_VHF);
  float*  ag  = (float*)(ws + OFF_AG);

  k_setup<<<dim3(5616), dim3(256), 0, stream>>>(x, W, w1, wd, xhf, xkh);
  for (int it = 0; it < 4; ++it) {
    k_g1sq<<<dim3(16, 10), dim3(1024), 0, stream>>>(xhf, w1, ag, vhfT, out, it);
    if (it < 3)
      k_g2<<<dim3(72, 2), dim3(512), 0, stream>>>(xkh, vhfT, wd, ag, it);
  }
}

// Round 14
// 121.259 us; speedup vs baseline: 1.4680x; 1.1634x over previous
//
#include <hip/hip_runtime.h>
#include <cstdint>
#include <cstddef>

typedef _Float16 half_t;
typedef __attribute__((ext_vector_type(8))) _Float16 f16x8;
typedef __attribute__((ext_vector_type(4))) _Float16 f16x4;
typedef __attribute__((ext_vector_type(4))) float f32x4;
typedef unsigned int uint_t;

// k-order: k = c*8 + i  (i innermost -> W-natural)
// Workspace offsets (bytes)
#define OFF_WH   0           // 1,474,560 f16 = 2,949,120
#define OFF_XHF  2949120     // 4,718,592
#define OFF_XKH  7667712     // 4,718,592
#define OFF_VHF  12386304    // 160*256 f16 = 81,920
#define OFF_AG   12468224    // 3it*10u*1152c f32 = 138,240
#define WS_NEED  12606464

// async 16B/lane global->LDS (lds dest = wave-uniform base + lane*16; global src per-lane)
__device__ __forceinline__ void gload16(const void* g, void* l) {
  __builtin_amdgcn_global_load_lds(
      (const __attribute__((address_space(1))) unsigned int*)g,
      (__attribute__((address_space(3))) unsigned int*)l, 16, 0, 0);
}

// ---------------- setup: wh (copy-convert) + xhf + xkh (all coalesced) ----------------
__global__ void k_setup(const float* __restrict__ x, const float* __restrict__ W,
                        half_t* __restrict__ wh, half_t* __restrict__ xhf,
                        half_t* __restrict__ xkh) {
  int bid = blockIdx.x, tid = threadIdx.x;
  if (bid < 720) {                       // wh: f16 copy of W, same linear layout
    int gid = bid * 256 + tid;           // 184320 x8-items
    const float4 a0 = *(const float4*)(W + (size_t)gid * 8);
    const float4 a1 = *(const float4*)(W + (size_t)gid * 8 + 4);
    f16x8 o;
    o[0] = (half_t)a0.x; o[1] = (half_t)a0.y; o[2] = (half_t)a0.z; o[3] = (half_t)a0.w;
    o[4] = (half_t)a1.x; o[5] = (half_t)a1.y; o[6] = (half_t)a1.z; o[7] = (half_t)a1.w;
    *(f16x8*)(wh + (size_t)gid * 8) = o;
  } else if (bid < 976) {                // xhf[b][c*8+i] = x[b][i][c], one block per b
    int b = bid - 720;
    __shared__ float lds_f[9216];
    const float4* xr = (const float4*)(x + (size_t)b * 9216);
    for (int t = tid; t < 2304; t += 256) {
      float4 v = xr[t];
      lds_f[t * 4 + 0] = v.x; lds_f[t * 4 + 1] = v.y;
      lds_f[t * 4 + 2] = v.z; lds_f[t * 4 + 3] = v.w;
    }
    __syncthreads();
    for (int t = tid; t < 1152; t += 256) {   // c = t, k chunk = c*8..c*8+7
      f16x8 o;
#pragma unroll
      for (int i = 0; i < 8; ++i) o[i] = (half_t)lds_f[i * 1152 + t];
      *(f16x8*)(xhf + (size_t)b * 9216 + t * 8) = o;
    }
  } else {                               // xkh[k][b] = x[b][i][c], 2304 tiles (32k x 32b)
    int tb = bid - 976;
    int kt = tb % 288, bt = tb / 288;
    int c0 = kt * 4, b0 = bt * 32;
    __shared__ float lt[32][36];
    int bl = tid >> 3, ch = tid & 7;     // b_local, i
    float4 v = *(const float4*)(x + (size_t)(b0 + bl) * 9216 + ch * 1152 + c0);
    lt[bl][0 * 8 + ch] = v.x;            // k_local = e*8 + i
    lt[bl][1 * 8 + ch] = v.y;
    lt[bl][2 * 8 + ch] = v.z;
    lt[bl][3 * 8 + ch] = v.w;
    __syncthreads();
    int kl = tid >> 3, bg = tid & 7;
    f16x4 h;
    h[0] = (half_t)lt[bg * 4 + 0][kl];
    h[1] = (half_t)lt[bg * 4 + 1][kl];
    h[2] = (half_t)lt[bg * 4 + 2][kl];
    h[3] = (half_t)lt[bg * 4 + 3][kl];
    *(f16x4*)(xkh + (size_t)(kt * 32 + kl) * 256 + b0 + bg * 4) = h;
  }
}

// ---------------- G1+squash: 16 waves, 3-buffer async staging, scalar cw ----------------
// grid (16 mb, 10 nt), 1024 thr; wave = 16 rows x 16 cols x 18 kt.
__global__ __launch_bounds__(1024) void k_g1sq(const half_t* __restrict__ xhf,
                                               const half_t* __restrict__ wh,
                                               const float* __restrict__ ag,
                                               half_t* __restrict__ vhfT,
                                               float* __restrict__ out, int it) {
  int mb = blockIdx.x, nt = blockIdx.y;
  int tid = threadIdx.x;
  int wv = tid >> 6, l = tid & 63, lm = l & 15, lgp = l >> 4;
  __shared__ __align__(16) half_t cwf[1152];            // scalar cw[c] for column nt
  __shared__ __align__(16) half_t stage[16][3][2][512]; // [wave][buf][x/w][1KB] = 96KB
  __shared__ __align__(16) float red[16][64][4];

  // prologue: softmax over u of (sum of compact ag slices)/256, keep column nt
  for (int c = tid; c < 1152; c += 1024) {
    float lv[10] = {0.f, 0.f, 0.f, 0.f, 0.f, 0.f, 0.f, 0.f, 0.f, 0.f};
    for (int t = 0; t < it; ++t)
#pragma unroll
      for (int u = 0; u < 10; ++u) lv[u] += ag[(size_t)(t * 10 + u) * 1152 + c];
    float mx = lv[0];
#pragma unroll
    for (int u = 1; u < 10; ++u) mx = fmaxf(mx, lv[u]);
    float ssum = 0.f, sel = 0.f;
#pragma unroll
    for (int u = 0; u < 10; ++u) {
      float e = __expf((lv[u] - mx) * (1.0f / 256.0f));
      ssum += e;
      if (u == nt) sel = e;
    }
    cwf[c] = (half_t)(sel / ssum);
  }
  __syncthreads();   // drains vmcnt -> counted waits below see only our loads

  // per-wave staging sources
  const half_t* xbase = xhf + (size_t)(mb * 16 + (l >> 2)) * 9216 + (l & 3) * 8;
  // w-frag lane l: wh + ((c*10+nt)*16+lm)*8, c = kt*4+lgp -> base + kt*5120
  const half_t* wbase = wh + ((size_t)(lgp * 10 + nt) * 16 + lm) * 8;
  int kt0 = wv * 18;
  int cbase = kt0 * 4 + lgp;
#define ISSUE(J)                                                                   \
  do {                                                                             \
    int kt_ = kt0 + (J);                                                           \
    gload16(xbase + (size_t)kt_ * 32, &stage[wv][(J) % 3][0][0]);                  \
    gload16(wbase + (size_t)kt_ * 5120, &stage[wv][(J) % 3][1][0]);                \
  } while (0)

  ISSUE(0);
  ISSUE(1);
  ISSUE(2);   // 6 outstanding, 3 buffers

  f32x4 acc0 = {0.f, 0.f, 0.f, 0.f};
  f32x4 acc1 = {0.f, 0.f, 0.f, 0.f};
#pragma unroll
  for (int j = 0; j < 18; ++j) {
    const int buf = j % 3;
    if (j <= 15) {
      asm volatile("s_waitcnt vmcnt(4)" ::: "memory");
    } else if (j == 16) {
      asm volatile("s_waitcnt vmcnt(2)" ::: "memory");
    } else {
      asm volatile("s_waitcnt vmcnt(0)" ::: "memory");
    }
    __builtin_amdgcn_sched_barrier(0);
    f16x8 af = *(const f16x8*)&stage[wv][buf][0][lm * 32 + lgp * 8];
    f16x8 wf = *(const f16x8*)&stage[wv][buf][1][l * 8];
    half_t sc = cwf[cbase + j * 4];
    f16x8 bsc = wf * sc;
    if ((j & 1) == 0) acc0 = __builtin_amdgcn_mfma_f32_16x16x32_f16(af, bsc, acc0, 0, 0, 0);
    else              acc1 = __builtin_amdgcn_mfma_f32_16x16x32_f16(af, bsc, acc1, 0, 0, 0);
    __builtin_amdgcn_sched_barrier(0);
    // issue-after-consume: ds_reads of buf retired before MFMA -> refill race-free
    if (j + 3 < 18) ISSUE(j + 3);
    __builtin_amdgcn_sched_barrier(0);
  }
#undef ISSUE
  acc0[0] += acc1[0]; acc0[1] += acc1[1]; acc0[2] += acc1[2]; acc0[3] += acc1[3];
  *(f32x4*)&red[wv][l][0] = acc0;
  __syncthreads();
  if (wv == 0) {
    float4 s = make_float4(0.f, 0.f, 0.f, 0.f);
#pragma unroll
    for (int w = 0; w < 16; ++w) {
      s.x += red[w][l][0]; s.y += red[w][l][1];
      s.z += red[w][l][2]; s.w += red[w][l][3];
    }
    float4 n2 = make_float4(s.x * s.x, s.y * s.y, s.z * s.z, s.w * s.w);
#pragma unroll
    for (int off = 1; off < 16; off <<= 1) {   // sum over o (lm lanes)
      n2.x += __shfl_xor(n2.x, off);
      n2.y += __shfl_xor(n2.y, off);
      n2.z += __shfl_xor(n2.z, off);
      n2.w += __shfl_xor(n2.w, off);
    }
    float4 vv;
    vv.x = s.x * (n2.x / ((1.f + n2.x) * sqrtf(n2.x)));
    vv.y = s.y * (n2.y / ((1.f + n2.y) * sqrtf(n2.y)));
    vv.z = s.z * (n2.z / ((1.f + n2.z) * sqrtf(n2.z)));
    vv.w = s.w * (n2.w / ((1.f + n2.w) * sqrtf(n2.w)));
    if (it == 3) {   // rows b = mb*16 + lgp*4 + r, col = nt*16 + lm
      float* ob = out + (size_t)(mb * 16 + lgp * 4) * 160 + nt * 16 + lm;
      ob[0 * 160] = vv.x; ob[1 * 160] = vv.y; ob[2 * 160] = vv.z; ob[3 * 160] = vv.w;
    } else {         // vhfT[n][b]
      f16x4 h;
      h[0] = (half_t)vv.x; h[1] = (half_t)vv.y; h[2] = (half_t)vv.z; h[3] = (half_t)vv.w;
      *(f16x4*)(vhfT + (size_t)(nt * 16 + lm) * 256 + mb * 16 + lgp * 4) = h;
    }
  }
}

// ---------------- G2: agreement, full-B per wave, direct-W epilogue -> ag[it][u][c] ----------------
// grid (144), 256 thr = 4 waves; wave = 1 mt tile (2 c's x 8 i), full b.
__global__ __launch_bounds__(256) void k_g2(const half_t* __restrict__ xkh,
                                            const half_t* __restrict__ vhfT,
                                            const float* __restrict__ W,
                                            float* __restrict__ ag, int it) {
  int cb = blockIdx.x;
  int tid = threadIdx.x;
  int wv = tid >> 6, l = tid & 63, lm = l & 15, lgp = l >> 4;
  int mt = cb * 4 + wv;                 // 0..575
  f32x4 z = {0.f, 0.f, 0.f, 0.f};
  f32x4 acc[10];
#pragma unroll
  for (int nt = 0; nt < 10; ++nt) acc[nt] = z;

#pragma unroll
  for (int bt = 0; bt < 8; ++bt) {
    f16x8 af = *(const f16x8*)(xkh + (size_t)(mt * 16 + lm) * 256 + bt * 32 + lgp * 8);
#pragma unroll
    for (int nt = 0; nt < 10; ++nt) {
      f16x8 bfr = *(const f16x8*)(vhfT + (size_t)(nt * 16 + lm) * 256 + bt * 32 + lgp * 8);
      acc[nt] = __builtin_amdgcn_mfma_f32_16x16x32_f16(af, bfr, acc[nt], 0, 0, 0);
    }
  }
  // epilogue: krow = mt*16 + lgp*4 + r -> c = mt*2 + (lgp>>1), i = (lgp&1)*4 + r
  int cc = mt * 2 + (lgp >> 1);
  int i0 = (lgp & 1) * 4;
  float* agt = ag + (size_t)it * 11520;
#pragma unroll
  for (int nt = 0; nt < 10; ++nt) {
    float4 wdv = *(const float4*)(W + ((size_t)(cc * 10 + nt) * 16 + lm) * 8 + i0);
    float q = acc[nt][0] * wdv.x + acc[nt][1] * wdv.y
            + acc[nt][2] * wdv.z + acc[nt][3] * wdv.w;
    q += __shfl_xor(q, 1);    // sum over o (lm)
    q += __shfl_xor(q, 2);
    q += __shfl_xor(q, 4);
    q += __shfl_xor(q, 8);
    q += __shfl_xor(q, 16);   // sum i-halves (lgp pairs)
    if (lm == 0 && (lgp & 1) == 0)   // lanes 0 (c0) and 32 (c1), single writer
      agt[(size_t)nt * 1152 + cc] = q;
  }
}

extern "C" void kernel_launch(void* const* d_in, const int* in_sizes, int n_in,
                              void* d_out, int out_size, void* d_ws, size_t ws_size,
                              hipStream_t stream) {
  const float* x = (const float*)d_in[0];
  const float* W = (const float*)d_in[1];
  float* out = (float*)d_out;
  char* ws = (char*)d_ws;
  if (ws_size < WS_NEED) return;   // output stays poisoned -> visible failure

  half_t* wh  = (half_t*)(ws + OFF_WH);
  half_t* xhf = (half_t*)(ws + OFF_XHF);
  half_t* xkh = (half_t*)(ws + OFF_XKH);
  half_t* vhfT= (half_t*)(ws + OFF_VHF);
  float*  ag  = (float*)(ws + OFF_AG);

  k_setup<<<dim3(3280), dim3(256), 0, stream>>>(x, W, wh, xhf, xkh);
  for (int it = 0; it < 4; ++it) {
    k_g1sq<<<dim3(16, 10), dim3(1024), 0, stream>>>(xhf, wh, ag, vhfT, out, it);
    if (it < 3)
      k_g2<<<dim3(144), dim3(256), 0, stream>>>(xkh, vhfT, W, ag, it);
  }
}

// Round 15
// 114.177 us; speedup vs baseline: 1.5590x; 1.0620x over previous
//
#include <hip/hip_runtime.h>
#include <cstdint>
#include <cstddef>

typedef _Float16 half_t;
typedef __attribute__((ext_vector_type(8))) _Float16 f16x8;
typedef __attribute__((ext_vector_type(4))) _Float16 f16x4;
typedef __attribute__((ext_vector_type(4))) float f32x4;
typedef unsigned int uint_t;

// k-order: k = c*8 + i  (i innermost -> W-natural)
// Workspace offsets (bytes)
#define OFF_WH   0           // 1,474,560 f16 = 2,949,120
#define OFF_XHF  2949120     // 4,718,592
#define OFF_XKH  7667712     // 4,718,592
#define OFF_VHF  12386304    // 160*256 f16 = 81,920
#define OFF_LG   12468224    // 10u*1152c f32 = 46,080 (running raw logit sums)
#define OFF_CWH  12514304    // 10u*1152c f16 = 23,040 (softmax coeffs, g2-produced)
#define WS_NEED  12537344

// async 16B/lane global->LDS (lds dest = wave-uniform base + lane*16; global src per-lane)
__device__ __forceinline__ void gload16(const void* g, void* l) {
  __builtin_amdgcn_global_load_lds(
      (const __attribute__((address_space(1))) unsigned int*)g,
      (__attribute__((address_space(3))) unsigned int*)l, 16, 0, 0);
}

// ---------------- setup: wh + xhf + xkh + lg=0 (one launch, 3325 blocks) ----------------
__global__ void k_setup(const float* __restrict__ x, const float* __restrict__ W,
                        half_t* __restrict__ wh, half_t* __restrict__ xhf,
                        half_t* __restrict__ xkh, float* __restrict__ lg) {
  int bid = blockIdx.x, tid = threadIdx.x;
  if (bid < 720) {                       // wh: f16 copy of W, same linear layout
    int gid = bid * 256 + tid;           // 184320 x8-items
    const float4 a0 = *(const float4*)(W + (size_t)gid * 8);
    const float4 a1 = *(const float4*)(W + (size_t)gid * 8 + 4);
    f16x8 o;
    o[0] = (half_t)a0.x; o[1] = (half_t)a0.y; o[2] = (half_t)a0.z; o[3] = (half_t)a0.w;
    o[4] = (half_t)a1.x; o[5] = (half_t)a1.y; o[6] = (half_t)a1.z; o[7] = (half_t)a1.w;
    *(f16x8*)(wh + (size_t)gid * 8) = o;
  } else if (bid < 976) {                // xhf[b][c*8+i] = x[b][i][c], one block per b
    int b = bid - 720;
    __shared__ float lds_f[9216];
    const float4* xr = (const float4*)(x + (size_t)b * 9216);
    for (int t = tid; t < 2304; t += 256) {
      float4 v = xr[t];
      lds_f[t * 4 + 0] = v.x; lds_f[t * 4 + 1] = v.y;
      lds_f[t * 4 + 2] = v.z; lds_f[t * 4 + 3] = v.w;
    }
    __syncthreads();
    for (int t = tid; t < 1152; t += 256) {   // c = t, k chunk = c*8..c*8+7
      f16x8 o;
#pragma unroll
      for (int i = 0; i < 8; ++i) o[i] = (half_t)lds_f[i * 1152 + t];
      *(f16x8*)(xhf + (size_t)b * 9216 + t * 8) = o;
    }
  } else if (bid < 3280) {               // xkh[k][b] = x[b][i][c], 2304 tiles (32k x 32b)
    int tb = bid - 976;
    int kt = tb % 288, bt = tb / 288;
    int c0 = kt * 4, b0 = bt * 32;
    __shared__ float lt[32][36];
    int bl = tid >> 3, ch = tid & 7;     // b_local, i
    float4 v = *(const float4*)(x + (size_t)(b0 + bl) * 9216 + ch * 1152 + c0);
    lt[bl][0 * 8 + ch] = v.x;            // k_local = e*8 + i
    lt[bl][1 * 8 + ch] = v.y;
    lt[bl][2 * 8 + ch] = v.z;
    lt[bl][3 * 8 + ch] = v.w;
    __syncthreads();
    int kl = tid >> 3, bg = tid & 7;
    f16x4 h;
    h[0] = (half_t)lt[bg * 4 + 0][kl];
    h[1] = (half_t)lt[bg * 4 + 1][kl];
    h[2] = (half_t)lt[bg * 4 + 2][kl];
    h[3] = (half_t)lt[bg * 4 + 3][kl];
    *(f16x4*)(xkh + (size_t)(kt * 32 + kl) * 256 + b0 + bg * 4) = h;
  } else {                               // zero running logits (45 blocks, 11520)
    lg[(bid - 3280) * 256 + tid] = 0.f;
  }
}

// ---------------- G1+squash: 16 waves, 4-buffer async staging, trivial cw load ----------------
// grid (16 mb, 10 nt), 1024 thr; wave = 16 rows x 16 cols x 18 kt.
__global__ __launch_bounds__(1024) void k_g1sq(const half_t* __restrict__ xhf,
                                               const half_t* __restrict__ wh,
                                               const half_t* __restrict__ cwh,
                                               half_t* __restrict__ vhfT,
                                               float* __restrict__ out, int it) {
  int mb = blockIdx.x, nt = blockIdx.y;
  int tid = threadIdx.x;
  int wv = tid >> 6, l = tid & 63, lm = l & 15, lgp = l >> 4;
  __shared__ __align__(16) half_t cwf[1152];            // scalar cw[c] for column nt
  __shared__ __align__(16) half_t stage[16][4][2][512]; // [wave][buf][x/w][1KB] = 128KB
  __shared__ __align__(16) float red[16][64][4];

  // prologue: cw for this nt — g2-produced (it>0) or the uniform softmax(0)=0.1 (it==0)
  if (it == 0) {
    for (int c = tid; c < 1152; c += 1024) cwf[c] = (half_t)0.1f;
  } else {
    for (int c = tid; c < 1152; c += 1024) cwf[c] = cwh[(size_t)nt * 1152 + c];
  }
  __syncthreads();   // drains vmcnt -> counted waits below see only our loads

  // per-wave staging sources
  const half_t* xbase = xhf + (size_t)(mb * 16 + (l >> 2)) * 9216 + (l & 3) * 8;
  const half_t* wbase = wh + ((size_t)(lgp * 10 + nt) * 16 + lm) * 8;  // + kt*5120
  int kt0 = wv * 18;
  int cbase = kt0 * 4 + lgp;
#define ISSUE(J)                                                                   \
  do {                                                                             \
    int kt_ = kt0 + (J);                                                           \
    gload16(xbase + (size_t)kt_ * 32, &stage[wv][(J) % 4][0][0]);                  \
    gload16(wbase + (size_t)kt_ * 5120, &stage[wv][(J) % 4][1][0]);                \
  } while (0)

  ISSUE(0);
  ISSUE(1);
  ISSUE(2);
  ISSUE(3);   // 8 outstanding, 4 buffers (depth-3 prefetch)

  f32x4 acc0 = {0.f, 0.f, 0.f, 0.f};
  f32x4 acc1 = {0.f, 0.f, 0.f, 0.f};
#pragma unroll
  for (int j = 0; j < 18; ++j) {
    const int buf = j % 4;
    if (j <= 14) {
      asm volatile("s_waitcnt vmcnt(6)" ::: "memory");
    } else if (j == 15) {
      asm volatile("s_waitcnt vmcnt(4)" ::: "memory");
    } else if (j == 16) {
      asm volatile("s_waitcnt vmcnt(2)" ::: "memory");
    } else {
      asm volatile("s_waitcnt vmcnt(0)" ::: "memory");
    }
    __builtin_amdgcn_sched_barrier(0);
    f16x8 af = *(const f16x8*)&stage[wv][buf][0][lm * 32 + lgp * 8];
    f16x8 wf = *(const f16x8*)&stage[wv][buf][1][l * 8];
    half_t sc = cwf[cbase + j * 4];
    f16x8 bsc = wf * sc;
    if ((j & 1) == 0) acc0 = __builtin_amdgcn_mfma_f32_16x16x32_f16(af, bsc, acc0, 0, 0, 0);
    else              acc1 = __builtin_amdgcn_mfma_f32_16x16x32_f16(af, bsc, acc1, 0, 0, 0);
    __builtin_amdgcn_sched_barrier(0);
    // issue-after-consume: ds_reads of buf retired before MFMA -> refill race-free
    if (j + 4 < 18) ISSUE(j + 4);
    __builtin_amdgcn_sched_barrier(0);
  }
#undef ISSUE
  acc0[0] += acc1[0]; acc0[1] += acc1[1]; acc0[2] += acc1[2]; acc0[3] += acc1[3];
  *(f32x4*)&red[wv][l][0] = acc0;
  __syncthreads();
  if (wv == 0) {
    float4 s = make_float4(0.f, 0.f, 0.f, 0.f);
#pragma unroll
    for (int w = 0; w < 16; ++w) {
      s.x += red[w][l][0]; s.y += red[w][l][1];
      s.z += red[w][l][2]; s.w += red[w][l][3];
    }
    float4 n2 = make_float4(s.x * s.x, s.y * s.y, s.z * s.z, s.w * s.w);
#pragma unroll
    for (int off = 1; off < 16; off <<= 1) {   // sum over o (lm lanes)
      n2.x += __shfl_xor(n2.x, off);
      n2.y += __shfl_xor(n2.y, off);
      n2.z += __shfl_xor(n2.z, off);
      n2.w += __shfl_xor(n2.w, off);
    }
    float4 vv;
    vv.x = s.x * (n2.x / ((1.f + n2.x) * sqrtf(n2.x)));
    vv.y = s.y * (n2.y / ((1.f + n2.y) * sqrtf(n2.y)));
    vv.z = s.z * (n2.z / ((1.f + n2.z) * sqrtf(n2.z)));
    vv.w = s.w * (n2.w / ((1.f + n2.w) * sqrtf(n2.w)));
    if (it == 3) {   // rows b = mb*16 + lgp*4 + r, col = nt*16 + lm
      float* ob = out + (size_t)(mb * 16 + lgp * 4) * 160 + nt * 16 + lm;
      ob[0 * 160] = vv.x; ob[1 * 160] = vv.y; ob[2 * 160] = vv.z; ob[3 * 160] = vv.w;
    } else {         // vhfT[n][b]
      f16x4 h;
      h[0] = (half_t)vv.x; h[1] = (half_t)vv.y; h[2] = (half_t)vv.z; h[3] = (half_t)vv.w;
      *(f16x4*)(vhfT + (size_t)(nt * 16 + lm) * 256 + mb * 16 + lgp * 4) = h;
    }
  }
}

// ---------------- G2: agreement + logit update + softmax -> cwh (and lg) ----------------
// grid (144), 256 thr = 4 waves; wave = 1 mt tile (2 c's x 8 i), full b.
__global__ __launch_bounds__(256) void k_g2(const half_t* __restrict__ xkh,
                                            const half_t* __restrict__ vhfT,
                                            const float* __restrict__ W,
                                            float* __restrict__ lg,
                                            half_t* __restrict__ cwh) {
  int cb = blockIdx.x;
  int tid = threadIdx.x;
  int wv = tid >> 6, l = tid & 63, lm = l & 15, lgp = l >> 4;
  int mt = cb * 4 + wv;                 // 0..575
  __shared__ float sm[8][10];
  f32x4 z = {0.f, 0.f, 0.f, 0.f};
  f32x4 acc[10];
#pragma unroll
  for (int nt = 0; nt < 10; ++nt) acc[nt] = z;

#pragma unroll
  for (int bt = 0; bt < 8; ++bt) {
    f16x8 af = *(const f16x8*)(xkh + (size_t)(mt * 16 + lm) * 256 + bt * 32 + lgp * 8);
#pragma unroll
    for (int nt = 0; nt < 10; ++nt) {
      f16x8 bfr = *(const f16x8*)(vhfT + (size_t)(nt * 16 + lm) * 256 + bt * 32 + lgp * 8);
      acc[nt] = __builtin_amdgcn_mfma_f32_16x16x32_f16(af, bfr, acc[nt], 0, 0, 0);
    }
  }
  // epilogue: krow = mt*16 + lgp*4 + r -> c = mt*2 + (lgp>>1), i = (lgp&1)*4 + r
  int cc = mt * 2 + (lgp >> 1);
  int i0 = (lgp & 1) * 4;
  int cl = wv * 2 + (lgp >> 1);         // c_local 0..7
#pragma unroll
  for (int nt = 0; nt < 10; ++nt) {
    float4 wdv = *(const float4*)(W + ((size_t)(cc * 10 + nt) * 16 + lm) * 8 + i0);
    float q = acc[nt][0] * wdv.x + acc[nt][1] * wdv.y
            + acc[nt][2] * wdv.z + acc[nt][3] * wdv.w;
    q += __shfl_xor(q, 1);    // sum over o (lm)
    q += __shfl_xor(q, 2);
    q += __shfl_xor(q, 4);
    q += __shfl_xor(q, 8);
    q += __shfl_xor(q, 16);   // sum i-halves (lgp pairs)
    if (lm == 0 && (lgp & 1) == 0) sm[cl][nt] = q;
  }
  __syncthreads();
  if (tid < 8) {   // per-c: logits += ag (raw), softmax(lg/256) -> cwh
    int c = cb * 8 + tid;
    float lv[10];
    float mx = -1e30f;
#pragma unroll
    for (int u = 0; u < 10; ++u) {
      float nlg = lg[(size_t)u * 1152 + c] + sm[tid][u];
      lg[(size_t)u * 1152 + c] = nlg;
      lv[u] = nlg;
      mx = fmaxf(mx, nlg);
    }
    float ssum = 0.f;
#pragma unroll
    for (int u = 0; u < 10; ++u) {
      lv[u] = __expf((lv[u] - mx) * (1.0f / 256.0f));
      ssum += lv[u];
    }
    float inv = 1.f / ssum;
#pragma unroll
    for (int u = 0; u < 10; ++u)
      cwh[(size_t)u * 1152 + c] = (half_t)(lv[u] * inv);
  }
}

extern "C" void kernel_launch(void* const* d_in, const int* in_sizes, int n_in,
                              void* d_out, int out_size, void* d_ws, size_t ws_size,
                              hipStream_t stream) {
  const float* x = (const float*)d_in[0];
  const float* W = (const float*)d_in[1];
  float* out = (float*)d_out;
  char* ws = (char*)d_ws;
  if (ws_size < WS_NEED) return;   // output stays poisoned -> visible failure

  half_t* wh  = (half_t*)(ws + OFF_WH);
  half_t* xhf = (half_t*)(ws + OFF_XHF);
  half_t* xkh = (half_t*)(ws + OFF_XKH);
  half_t* vhfT= (half_t*)(ws + OFF_VHF);
  float*  lg  = (float*)(ws + OFF_LG);
  half_t* cwh = (half_t*)(ws + OFF_CWH);

  k_setup<<<dim3(3325), dim3(256), 0, stream>>>(x, W, wh, xhf, xkh, lg);
  for (int it = 0; it < 4; ++it) {
    k_g1sq<<<dim3(16, 10), dim3(1024), 0, stream>>>(xhf, wh, cwh, vhfT, out, it);
    if (it < 3)
      k_g2<<<dim3(144), dim3(256), 0, stream>>>(xkh, vhfT, W, lg, cwh);
  }
}